// Round 17
// baseline (195.441 us; speedup 1.0000x reference)
//
#include <hip/hip_runtime.h>

// ALiBi attention block, MI355X. B=2, T=2048, C=1024, NH=16, HD=64.
// fp32 in / fp32 out; bf16 MFMA compute.  (r16 best: 190.84 us)
// Pipeline: prep (convert x + transpose weights, fused) | fused QKV GEMM
// (256x128 tile, 384 blocks full fill, 2-slot dbuf 48 KB -> 3 blocks/CU)
// | paired flash attn (r9 body + XCD-locality remap + ISOLATED exp2-fold:
// constants only, register-neutral) | out-proj GEMM (128x128 4-slot ring).
// ws (u16): wqkvT[0,3M) woT[3M,4M) xc[4M,8M) qbuf[8M,12M) vtbuf[12M,16M).
// K staged bf16 in d_out (16 MB fp32 buf), overwritten by final GEMM.

typedef unsigned short u16;
typedef unsigned int u32;
typedef __attribute__((ext_vector_type(8))) short bf16x8;      // 8 bf16 = 4 VGPR
typedef __attribute__((ext_vector_type(4))) float f32x4;
typedef __attribute__((ext_vector_type(4))) unsigned short u16x4;

#define MFMA16x16(A, B, C_) __builtin_amdgcn_mfma_f32_16x16x32_bf16((A), (B), (C_), 0, 0, 0)

__device__ __forceinline__ u16 f2bf(float f) {
  u32 x = __builtin_bit_cast(u32, f);
  x += 0x7fff + ((x >> 16) & 1);   // RNE
  return (u16)(x >> 16);
}

// async global->LDS, 16B/lane; LDS dest = wave-uniform base + lane*16
__device__ __forceinline__ void gload_lds16(const u16* g, u16* l) {
  __builtin_amdgcn_global_load_lds(
      (const __attribute__((address_space(1))) void*)g,
      (__attribute__((address_space(3))) void*)l, 16, 0, 0);
}

constexpr int T = 2048, C = 1024, HD = 64;
constexpr int BT = 2 * T;  // 4096

// XOR-swizzled frag read: element (row, k) lives at chunk (k>>3)^(row&7).
__device__ __forceinline__ bf16x8 ldsfrag(const u16* lds, int row, int kchunk) {
  return *(const bf16x8*)(lds + row * 64 + (((kchunk) ^ (row & 7)) << 3));
}

// ---------------- prep: convert x -> bf16 AND transpose 4 weights ----------
// blocks [0,2048): convert; blocks [2048,6144): transpose (1024 per weight).
__global__ __launch_bounds__(256) void prep_kernel(
    const float* __restrict__ xin, u16* __restrict__ xc,
    const float* __restrict__ w0, const float* __restrict__ w1,
    const float* __restrict__ w2, const float* __restrict__ w3,
    u16* __restrict__ wqkvT, u16* __restrict__ woT) {
  __shared__ u16 tile[32][33];
  const int bz = blockIdx.x, tid = threadIdx.x;
  if (bz < 2048) {
    int i = (bz * 256 + tid) * 8;
    const float4 a = *(const float4*)(xin + i);
    const float4 b = *(const float4*)(xin + i + 4);
    uint4 o;
    o.x = (u32)f2bf(a.x) | ((u32)f2bf(a.y) << 16);
    o.y = (u32)f2bf(a.z) | ((u32)f2bf(a.w) << 16);
    o.z = (u32)f2bf(b.x) | ((u32)f2bf(b.y) << 16);
    o.w = (u32)f2bf(b.z) | ((u32)f2bf(b.w) << 16);
    *(uint4*)(xc + i) = o;
    return;
  }
  const int t = bz - 2048;
  const int z = t >> 10, rem = t & 1023;
  const int bx = rem & 31, by = rem >> 5;
  const float* in = (z == 0) ? w0 : (z == 1) ? w1 : (z == 2) ? w2 : w3;
  u16* out = (z < 3) ? (wqkvT + (size_t)z * (1u << 20)) : woT;
  const int tx = tid & 31, ty = tid >> 5;
  int x = bx * 32 + tx;
#pragma unroll
  for (int i = 0; i < 4; i++) {
    int y = by * 32 + ty + i * 8;
    tile[ty + i * 8][tx] = f2bf(in[y * 1024 + x]);
  }
  __syncthreads();
  int xo = by * 32 + tx;
#pragma unroll
  for (int i = 0; i < 4; i++) {
    int yo = bx * 32 + ty + i * 8;
    out[yo * 1024 + xo] = tile[tx][ty + i * 8];
  }
}

// ---------------- fused QKV GEMM: 256x128 tile, 2-slot double buffer -------
// Bt = [WqT;WkT;WvT] (N=3072). n0<1024 -> Q bf16; <2048 -> K bf16;
// else V written TRANSPOSED to vtout[c][m].
// 384 blocks (16Mx24N) = full CU fill; 48 KB LDS -> 3 blocks/CU TLP.
// 8 waves as 4(M) x 2(N), wave tile 64x64, acc[4][4].
__global__ __launch_bounds__(512, 2) void gemm_qkv_kernel(
    const u16* __restrict__ A, const u16* __restrict__ Bt,
    const float* __restrict__ b0, const float* __restrict__ b1,
    const float* __restrict__ b2,
    u16* __restrict__ qout, u16* __restrict__ kout, u16* __restrict__ vtout) {
  constexpr int K = 1024, BK = 32, NT = K / BK;   // NT = 32
  __shared__ __align__(16) u16 As[2][256 * BK];   // 32 KiB
  __shared__ __align__(16) u16 Bs[2][128 * BK];   // 16 KiB

  const int tid = threadIdx.x;
  const int w = tid >> 6, lane = tid & 63;
  const int l15 = lane & 15, quad = lane >> 4;
  const int wr = w >> 1, wc = w & 1;           // 4(M) x 2(N) wave grid
  // XCD-aware swizzle (384 blocks, 384 = 8*48 -> bijective)
  const int bid = blockIdx.y * 24 + blockIdx.x;
  const int swz = (bid & 7) * 48 + (bid >> 3);
  const int m0 = (swz / 24) * 256, n0 = (swz % 24) * 128;
  const int rw = lane >> 2;                    // staging row-in-16
  const int pc = lane & 3;                     // staging phys chunk

  const u16* Ag = A + (size_t)m0 * K;
  const u16* Bg = Bt + (size_t)n0 * K;

  f32x4 acc[4][4] = {};

  // 3 gloads/wave: A rows [w*32, w*32+32) (2 loads), B rows [w*16, w*16+16)
  auto STAGE = [&](int kt, int s) {
#pragma unroll
    for (int j = 0; j < 2; j++) {
      int row = w * 32 + j * 16 + rw;
      int cl = pc ^ (row & 3);
      gload_lds16(Ag + (size_t)row * K + kt * BK + cl * 8,
                  &As[s][(w * 32 + j * 16) * BK]);
    }
    {
      int row = w * 16 + rw;
      int cl = pc ^ (row & 3);
      gload_lds16(Bg + (size_t)row * K + kt * BK + cl * 8,
                  &Bs[s][(w * 16) * BK]);
    }
  };

  STAGE(0, 0);
  asm volatile("s_waitcnt vmcnt(0)" ::: "memory");
  __builtin_amdgcn_s_barrier();

#pragma unroll 1
  for (int t = 0; t < NT; ++t) {
    const int s = t & 1;
    if (t + 1 < NT) STAGE(t + 1, s ^ 1);

    const u16* Asl = As[s];
    const u16* Bsl = Bs[s];
    bf16x8 bfr[4], afr[4];
#pragma unroll
    for (int ni = 0; ni < 4; ni++) {
      int row = wc * 64 + ni * 16 + l15;
      bfr[ni] = *(const bf16x8*)(Bsl + row * BK + ((quad ^ (row & 3)) << 3));
    }
#pragma unroll
    for (int mi = 0; mi < 4; mi++) {
      int row = wr * 64 + mi * 16 + l15;
      afr[mi] = *(const bf16x8*)(Asl + row * BK + ((quad ^ (row & 3)) << 3));
    }
    __builtin_amdgcn_s_setprio(1);
#pragma unroll
    for (int mi = 0; mi < 4; mi++)
#pragma unroll
      for (int ni = 0; ni < 4; ni++)
        acc[mi][ni] = MFMA16x16(afr[mi], bfr[ni], acc[mi][ni]);
    __builtin_amdgcn_s_setprio(0);

    if (t + 1 < NT) {
      asm volatile("s_waitcnt vmcnt(0)" ::: "memory");  // t+1 staged
      __builtin_amdgcn_s_barrier();
    }
  }

  const int sel = n0 >> 10;       // 0=Q,1=K,2=V (128-tile never straddles)
  const int nloc = n0 & 1023;
  if (sel < 2) {
    u16* D = (sel == 0) ? qout : kout;
    const float* bias = (sel == 0) ? b0 : b1;
#pragma unroll
    for (int mi = 0; mi < 4; mi++)
#pragma unroll
      for (int ni = 0; ni < 4; ni++) {
        int rb = m0 + wr * 64 + mi * 16 + quad * 4;
        int col = nloc + wc * 64 + ni * 16 + l15;
        float bb = bias[col];
#pragma unroll
        for (int r = 0; r < 4; r++)
          D[(size_t)(rb + r) * 1024 + col] = f2bf(acc[mi][ni][r] + bb);
      }
  } else {
#pragma unroll
    for (int mi = 0; mi < 4; mi++)
#pragma unroll
      for (int ni = 0; ni < 4; ni++) {
        int rb = m0 + wr * 64 + mi * 16 + quad * 4;
        int c = nloc + wc * 64 + ni * 16 + l15;
        float bb = b2[c];
        u16x4 pk;
#pragma unroll
        for (int r = 0; r < 4; r++) pk[r] = f2bf(acc[mi][ni][r] + bb);
        *(u16x4*)(vtout + (size_t)c * 4096 + rb) = pk;
      }
  }
}

// ---------------- out-proj GEMM: 128x128 tile, BK=32, 4-slot ring ----------
// (r14/r16 version — measured best) 4 gloads/wave/stage -> vmcnt(8/4/0)
// counted waits keep 2 K-tiles in flight across barriers. 256 thr =
// 4 waves (2M x 2N), 64 KB LDS.
__global__ __launch_bounds__(256, 2) void gemm_out_kernel(
    const u16* __restrict__ A, const u16* __restrict__ Bt,
    const float* __restrict__ bias, float* __restrict__ fout) {
  constexpr int K = 1024, BK = 32, NT = K / BK;   // NT = 32
  __shared__ __align__(16) u16 ring[4][2][128 * BK];   // 64 KiB

  const int tid = threadIdx.x;
  const int w = tid >> 6, lane = tid & 63;
  const int l15 = lane & 15, quad = lane >> 4;
  const int wr = w >> 1, wc = w & 1;           // 2(M) x 2(N) wave grid
  // XCD-aware swizzle (256 blocks, %8==0 -> simple form bijective)
  const int bid = blockIdx.y * 8 + blockIdx.x;
  const int swz = (bid & 7) * 32 + (bid >> 3);
  const int m0 = (swz >> 3) * 128, n0 = (swz & 7) * 128;
  const int rw = lane >> 2;                    // staging row-in-16
  const int pc = lane & 3;                     // staging phys chunk

  const u16* Ag = A + (size_t)m0 * K;
  const u16* Bg = Bt + (size_t)n0 * K;

  f32x4 acc[4][4] = {};

  auto STAGE = [&](int kt, int s) {
#pragma unroll
    for (int j = 0; j < 2; j++) {
      int row = j * 64 + w * 16 + rw;
      int cl = pc ^ (row & 3);
      gload_lds16(Ag + (size_t)row * K + kt * BK + cl * 8,
                  &ring[s][0][(j * 64 + w * 16) * BK]);
      gload_lds16(Bg + (size_t)row * K + kt * BK + cl * 8,
                  &ring[s][1][(j * 64 + w * 16) * BK]);
    }
  };

  STAGE(0, 0); STAGE(1, 1); STAGE(2, 2);
  asm volatile("s_waitcnt vmcnt(8)" ::: "memory");
  __builtin_amdgcn_s_barrier();

#pragma unroll 1
  for (int t = 0; t < NT; ++t) {
    const int s = t & 3;
    if (t + 3 < NT) STAGE(t + 3, (t + 3) & 3);

    const u16* As = ring[s][0];
    const u16* Bs = ring[s][1];
    bf16x8 bfr[4], afr[4];
#pragma unroll
    for (int ni = 0; ni < 4; ni++) {
      int row = wc * 64 + ni * 16 + l15;
      bfr[ni] = *(const bf16x8*)(Bs + row * BK + ((quad ^ (row & 3)) << 3));
    }
#pragma unroll
    for (int mi = 0; mi < 4; mi++) {
      int row = wr * 64 + mi * 16 + l15;
      afr[mi] = *(const bf16x8*)(As + row * BK + ((quad ^ (row & 3)) << 3));
    }
    __builtin_amdgcn_s_setprio(1);
#pragma unroll
    for (int mi = 0; mi < 4; mi++)
#pragma unroll
      for (int ni = 0; ni < 4; ni++)
        acc[mi][ni] = MFMA16x16(afr[mi], bfr[ni], acc[mi][ni]);
    __builtin_amdgcn_s_setprio(0);

    if (t + 3 < NT)
      asm volatile("s_waitcnt vmcnt(8)" ::: "memory");
    else if (t + 2 < NT)
      asm volatile("s_waitcnt vmcnt(4)" ::: "memory");
    else if (t + 1 < NT)
      asm volatile("s_waitcnt vmcnt(0)" ::: "memory");
    if (t + 1 < NT) __builtin_amdgcn_s_barrier();
  }

#pragma unroll
  for (int mi = 0; mi < 4; mi++)
#pragma unroll
    for (int ni = 0; ni < 4; ni++) {
      int rb = m0 + wr * 64 + mi * 16 + quad * 4;
      int col = n0 + wc * 64 + ni * 16 + l15;
      float bb = bias[col];
#pragma unroll
      for (int r = 0; r < 4; r++)
        fout[(size_t)(rb + r) * 1024 + col] = acc[mi][ni][r] + bb;
    }
}

// ---------------- paired flash attention, j-split wave groups ----------------
// r9 body + XCD-locality remap (r13) + ISOLATED exp2-domain softmax fold:
// slope2 = slope*log2e, scale 0.125*log2e — constants only, no new live
// state (r8's spill came from the bundled lambda-peel, not the fold).
// 64 VGPR, no spill, reg-Q, 48 KB LDS; FETCH 14.6 MB (K/V L2-resident).
__global__ __launch_bounds__(512, 4) void attn_kernel(
    const u16* __restrict__ qbuf, const u16* __restrict__ kbuf,
    const u16* __restrict__ vtbuf, u16* __restrict__ ybuf) {
  __shared__ __align__(16) u16 KVs[4][64 * 64];    // 32 KB: K0,K1,V0,V1
  __shared__ __align__(16) u16 Ps[8][16 * 64];     // 16 KB per-wave P

  const int tid = threadIdx.x;
  const int w = tid >> 6, lane = tid & 63;
  const int wq = w & 3, g = w >> 2;
  const int l15 = lane & 15, quad = lane >> 4;
  // XCD-locality remap: id -> (xcd = id&7, x = (id>>3)&15, bhl = id>>7);
  // bh = xcd*4 + bhl. Bijective on [0,512).
  const int id = (int)blockIdx.x;
  const int bh = (id & 7) * 4 + (id >> 7);
  const int qx = (id >> 3) & 15;
  const int b = bh >> 4, h = bh & 15;
  constexpr float LOG2E = 1.44269504f;
  const float slope2 = exp2f(-0.5f * (float)(h + 1)) * LOG2E;  // log2-domain
  const float slope128 = slope2 * 128.f;
  const int gsub = (lane & 7) ^ ((lane >> 3) & 7);
  const int rsub = lane >> 3;

  const u16* kbase0 = kbuf + (size_t)b * T * C + h * HD;
  const u16* vtbase0 = vtbuf + (size_t)h * HD * BT + (size_t)b * T;
  u16* Pw = Ps[w];
  // staging role: tile t = w>>1 (0=K of jt0, 1=V of jt0, 2=K of jt1, 3=V of jt1)
  const int st = w >> 1;
  const int skind = st & 1;          // 0=K, 1=V
  const int sjt = st >> 1;           // which j-tile of the pair
  const int srb = (w & 1) * 32;      // 32 rows per wave

#pragma unroll 1
  for (int half = 0; half < 2; half++) {
    const int qt = half == 0 ? (31 - qx) : qx;

    // Q fragments straight from global: lane reads its own output row
    // (qt*64 + wq*16 + l15), 16B at cols [quad*8, quad*8+8) and +32.
    const u16* qb = qbuf + (size_t)(b * T + qt * 64 + wq * 16 + l15) * C + h * HD;
    bf16x8 aq0 = *(const bf16x8*)(qb + quad * 8);
    bf16x8 aq1 = *(const bf16x8*)(qb + 32 + quad * 8);

    f32x4 o[4] = {};
    float lsum[4] = {0.f, 0.f, 0.f, 0.f};
    // br[ni][r] = slope2*(j - i) at jt = g (virtual), advances 2 tiles/iter
    float br[4][4];
    const int ig0 = qt * 64 + wq * 16 + quad * 4;
#pragma unroll
    for (int ni = 0; ni < 4; ni++)
#pragma unroll
      for (int r = 0; r < 4; r++)
        br[ni][r] = slope2 * (float)(g * 64 + ni * 16 + l15 - ig0 - r);

    const int iters = (qt + 2) >> 1;   // ceil((qt+1)/2)
#pragma unroll 1
    for (int it = 0; it < iters; it++) {
      __syncthreads();  // all waves done with previous K/V frag reads
                        // (and, at it=0, with the prior half's LDS scratch)
      {
        int jtv = 2 * it + sjt;
        int jtr = jtv > qt ? qt : jtv;     // clamp: no OOB, contribution masked
        const u16* base = skind ? (vtbase0 + jtr * 64)
                                : (kbase0 + (size_t)jtr * 64 * C);
        const int stride = skind ? BT : C;
        u16* dst = KVs[skind * 2 + sjt] + srb * 64;
#pragma unroll
        for (int c2 = 0; c2 < 4; c2++)
          gload_lds16(base + (size_t)(srb + c2 * 8 + rsub) * stride + gsub * 8,
                      dst + c2 * 8 * 64);
      }
      __syncthreads();  // staging visible

      const int jtv = 2 * it + g;        // this group's virtual j-tile
      const u16* Kw = KVs[g];
      const u16* Vw = KVs[2 + g];

      // S[16x64] = Q K^T
      f32x4 s[4];
#pragma unroll
      for (int ni = 0; ni < 4; ni++) {
        bf16x8 kf0 = ldsfrag(Kw, ni * 16 + l15, quad);
        bf16x8 kf1 = ldsfrag(Kw, ni * 16 + l15, 4 + quad);
        f32x4 z = {0.f, 0.f, 0.f, 0.f};
        z = MFMA16x16(aq0, kf0, z);
        z = MFMA16x16(aq1, kf1, z);
        s[ni] = z;
      }

      const bool edge = (jtv >= qt);     // diagonal or dead (jtv>qt)
#pragma unroll
      for (int ni = 0; ni < 4; ni++)
#pragma unroll
        for (int r = 0; r < 4; r++) {
          // exp2-domain: p = 2^(s*0.125*log2e + slope2*(j-i))
          float p = exp2f(fmaf(s[ni][r], 0.125f * LOG2E, br[ni][r]));
          // mask by virtual global j vs i (covers diag + dead uniformly)
          if (edge && (jtv * 64 + ni * 16 + l15) > (ig0 + r)) p = 0.f;
          lsum[r] += p;
          int prow = quad * 4 + r, pcol = ni * 16 + l15;
          Pw[prow * 64 + (((pcol >> 3) ^ (prow & 7)) << 3) + (pcol & 7)] = f2bf(p);
          br[ni][r] += slope128;
        }

      bf16x8 pa0 = ldsfrag(Pw, l15, quad);
      bf16x8 pa1 = ldsfrag(Pw, l15, 4 + quad);
#pragma unroll
      for (int ni = 0; ni < 4; ni++) {
        bf16x8 vf0 = ldsfrag(Vw, ni * 16 + l15, quad);
        bf16x8 vf1 = ldsfrag(Vw, ni * 16 + l15, 4 + quad);
        o[ni] = MFMA16x16(pa0, vf0, o[ni]);
        o[ni] = MFMA16x16(pa1, vf1, o[ni]);
      }
    }

    // combine the two groups (pure sums), then normalize + write y
    __syncthreads();  // KVs now reusable as f32 scratch
    float* sc = (float*)KVs;           // 32 KB scratch
    float* Osc = sc + wq * 1024;       // [16 rows][64 d] per wq
    float* Lsc = sc + 4096 + wq * 256; // [16 rows][16 cols] per wq
    if (g == 1) {
#pragma unroll
      for (int ni = 0; ni < 4; ni++)
#pragma unroll
        for (int r = 0; r < 4; r++)
          Osc[(quad * 4 + r) * 64 + ni * 16 + l15] = o[ni][r];
#pragma unroll
      for (int r = 0; r < 4; r++)
        Lsc[(quad * 4 + r) * 16 + l15] = lsum[r];
    }
    __syncthreads();
    if (g == 0) {
#pragma unroll
      for (int ni = 0; ni < 4; ni++)
#pragma unroll
        for (int r = 0; r < 4; r++)
          o[ni][r] += Osc[(quad * 4 + r) * 64 + ni * 16 + l15];
#pragma unroll
      for (int r = 0; r < 4; r++) {
        float l = lsum[r] + Lsc[(quad * 4 + r) * 16 + l15];
        l += __shfl_xor(l, 1);
        l += __shfl_xor(l, 2);
        l += __shfl_xor(l, 4);
        l += __shfl_xor(l, 8);
        float inv = 1.f / l;
        int row_g = b * T + qt * 64 + wq * 16 + quad * 4 + r;
        u16* yrow = ybuf + (size_t)row_g * C + h * HD;
#pragma unroll
        for (int ni = 0; ni < 4; ni++)
          yrow[ni * 16 + l15] = f2bf(o[ni][r] * inv);
      }
    }
  }
}

extern "C" void kernel_launch(void* const* d_in, const int* in_sizes, int n_in,
                              void* d_out, int out_size, void* d_ws, size_t ws_size,
                              hipStream_t stream) {
  (void)in_sizes; (void)n_in; (void)out_size; (void)ws_size;
  const float* x  = (const float*)d_in[0];
  const float* Wq = (const float*)d_in[1];
  const float* bq = (const float*)d_in[2];
  const float* Wk = (const float*)d_in[3];
  const float* bk = (const float*)d_in[4];
  const float* Wv = (const float*)d_in[5];
  const float* bv = (const float*)d_in[6];
  const float* Wo = (const float*)d_in[7];
  const float* bo = (const float*)d_in[8];

  u16* ws = (u16*)d_ws;
  constexpr size_t M1 = 1u << 20;
  u16* wqkvT = ws;               // [3072,1024] = [WqT;WkT;WvT]
  u16* woT   = ws + 3 * M1;      // [1024,1024]
  u16* xc    = ws + 4 * M1;      // [4096,1024] bf16 x
  u16* qbuf  = ws + 8 * M1;      // [4096,1024] bf16 Q (later aliased as y)
  u16* vtbuf = ws + 12 * M1;     // [1024,4096] bf16 V^T
  u16* kbuf  = (u16*)d_out;      // bf16 K staged in d_out (16 MB fp32 buffer)
  u16* ybuf  = qbuf;             // safe alias: block overwrites only its own Q tiles

  prep_kernel<<<6144, 256, 0, stream>>>(x, xc, Wq, Wk, Wv, Wo, wqkvT, woT);
  gemm_qkv_kernel<<<dim3(24, 16), 512, 0, stream>>>(
      xc, wqkvT, bq, bk, bv, qbuf, kbuf, vtbuf);
  attn_kernel<<<dim3(512), 512, 0, stream>>>(qbuf, kbuf, vtbuf, ybuf);
  gemm_out_kernel<<<dim3(8, 32), 256, 0, stream>>>(ybuf, woT, bo, (float*)d_out);
}

// Round 18
// 189.890 us; speedup vs baseline: 1.0292x; 1.0292x over previous
//
#include <hip/hip_runtime.h>

// ALiBi attention block, MI355X. B=2, T=2048, C=1024, NH=16, HD=64.
// fp32 in / fp32 out; bf16 MFMA compute.  (r16 best config: 190.84 us)
// Pipeline: prep (convert x + transpose weights, fused) | fused QKV GEMM
// (256x128 tile, 384 blocks full fill, 2-slot dbuf 48 KB -> 3 blocks/CU)
// | paired flash attn (r9 body + XCD-locality remap, K/V L2-resident;
// __expf softmax — exp2f regressed: libm exp2f is multi-inst vs native)
// | out-proj GEMM (128x128 tile, 4-slot counted ring).
// ws (u16): wqkvT[0,3M) woT[3M,4M) xc[4M,8M) qbuf[8M,12M) vtbuf[12M,16M).
// K staged bf16 in d_out (16 MB fp32 buf), overwritten by final GEMM.

typedef unsigned short u16;
typedef unsigned int u32;
typedef __attribute__((ext_vector_type(8))) short bf16x8;      // 8 bf16 = 4 VGPR
typedef __attribute__((ext_vector_type(4))) float f32x4;
typedef __attribute__((ext_vector_type(4))) unsigned short u16x4;

#define MFMA16x16(A, B, C_) __builtin_amdgcn_mfma_f32_16x16x32_bf16((A), (B), (C_), 0, 0, 0)

__device__ __forceinline__ u16 f2bf(float f) {
  u32 x = __builtin_bit_cast(u32, f);
  x += 0x7fff + ((x >> 16) & 1);   // RNE
  return (u16)(x >> 16);
}

// async global->LDS, 16B/lane; LDS dest = wave-uniform base + lane*16
__device__ __forceinline__ void gload_lds16(const u16* g, u16* l) {
  __builtin_amdgcn_global_load_lds(
      (const __attribute__((address_space(1))) void*)g,
      (__attribute__((address_space(3))) void*)l, 16, 0, 0);
}

constexpr int T = 2048, C = 1024, HD = 64;
constexpr int BT = 2 * T;  // 4096

// XOR-swizzled frag read: element (row, k) lives at chunk (k>>3)^(row&7).
__device__ __forceinline__ bf16x8 ldsfrag(const u16* lds, int row, int kchunk) {
  return *(const bf16x8*)(lds + row * 64 + (((kchunk) ^ (row & 7)) << 3));
}

// ---------------- prep: convert x -> bf16 AND transpose 4 weights ----------
// blocks [0,2048): convert; blocks [2048,6144): transpose (1024 per weight).
__global__ __launch_bounds__(256) void prep_kernel(
    const float* __restrict__ xin, u16* __restrict__ xc,
    const float* __restrict__ w0, const float* __restrict__ w1,
    const float* __restrict__ w2, const float* __restrict__ w3,
    u16* __restrict__ wqkvT, u16* __restrict__ woT) {
  __shared__ u16 tile[32][33];
  const int bz = blockIdx.x, tid = threadIdx.x;
  if (bz < 2048) {
    int i = (bz * 256 + tid) * 8;
    const float4 a = *(const float4*)(xin + i);
    const float4 b = *(const float4*)(xin + i + 4);
    uint4 o;
    o.x = (u32)f2bf(a.x) | ((u32)f2bf(a.y) << 16);
    o.y = (u32)f2bf(a.z) | ((u32)f2bf(a.w) << 16);
    o.z = (u32)f2bf(b.x) | ((u32)f2bf(b.y) << 16);
    o.w = (u32)f2bf(b.z) | ((u32)f2bf(b.w) << 16);
    *(uint4*)(xc + i) = o;
    return;
  }
  const int t = bz - 2048;
  const int z = t >> 10, rem = t & 1023;
  const int bx = rem & 31, by = rem >> 5;
  const float* in = (z == 0) ? w0 : (z == 1) ? w1 : (z == 2) ? w2 : w3;
  u16* out = (z < 3) ? (wqkvT + (size_t)z * (1u << 20)) : woT;
  const int tx = tid & 31, ty = tid >> 5;
  int x = bx * 32 + tx;
#pragma unroll
  for (int i = 0; i < 4; i++) {
    int y = by * 32 + ty + i * 8;
    tile[ty + i * 8][tx] = f2bf(in[y * 1024 + x]);
  }
  __syncthreads();
  int xo = by * 32 + tx;
#pragma unroll
  for (int i = 0; i < 4; i++) {
    int yo = bx * 32 + ty + i * 8;
    out[yo * 1024 + xo] = tile[tx][ty + i * 8];
  }
}

// ---------------- fused QKV GEMM: 256x128 tile, 2-slot double buffer -------
// Bt = [WqT;WkT;WvT] (N=3072). n0<1024 -> Q bf16; <2048 -> K bf16;
// else V written TRANSPOSED to vtout[c][m].
// 384 blocks (16Mx24N) = full CU fill; 48 KB LDS -> 3 blocks/CU TLP.
// 8 waves as 4(M) x 2(N), wave tile 64x64, acc[4][4].
__global__ __launch_bounds__(512, 2) void gemm_qkv_kernel(
    const u16* __restrict__ A, const u16* __restrict__ Bt,
    const float* __restrict__ b0, const float* __restrict__ b1,
    const float* __restrict__ b2,
    u16* __restrict__ qout, u16* __restrict__ kout, u16* __restrict__ vtout) {
  constexpr int K = 1024, BK = 32, NT = K / BK;   // NT = 32
  __shared__ __align__(16) u16 As[2][256 * BK];   // 32 KiB
  __shared__ __align__(16) u16 Bs[2][128 * BK];   // 16 KiB

  const int tid = threadIdx.x;
  const int w = tid >> 6, lane = tid & 63;
  const int l15 = lane & 15, quad = lane >> 4;
  const int wr = w >> 1, wc = w & 1;           // 4(M) x 2(N) wave grid
  // XCD-aware swizzle (384 blocks, 384 = 8*48 -> bijective)
  const int bid = blockIdx.y * 24 + blockIdx.x;
  const int swz = (bid & 7) * 48 + (bid >> 3);
  const int m0 = (swz / 24) * 256, n0 = (swz % 24) * 128;
  const int rw = lane >> 2;                    // staging row-in-16
  const int pc = lane & 3;                     // staging phys chunk

  const u16* Ag = A + (size_t)m0 * K;
  const u16* Bg = Bt + (size_t)n0 * K;

  f32x4 acc[4][4] = {};

  // 3 gloads/wave: A rows [w*32, w*32+32) (2 loads), B rows [w*16, w*16+16)
  auto STAGE = [&](int kt, int s) {
#pragma unroll
    for (int j = 0; j < 2; j++) {
      int row = w * 32 + j * 16 + rw;
      int cl = pc ^ (row & 3);
      gload_lds16(Ag + (size_t)row * K + kt * BK + cl * 8,
                  &As[s][(w * 32 + j * 16) * BK]);
    }
    {
      int row = w * 16 + rw;
      int cl = pc ^ (row & 3);
      gload_lds16(Bg + (size_t)row * K + kt * BK + cl * 8,
                  &Bs[s][(w * 16) * BK]);
    }
  };

  STAGE(0, 0);
  asm volatile("s_waitcnt vmcnt(0)" ::: "memory");
  __builtin_amdgcn_s_barrier();

#pragma unroll 1
  for (int t = 0; t < NT; ++t) {
    const int s = t & 1;
    if (t + 1 < NT) STAGE(t + 1, s ^ 1);

    const u16* Asl = As[s];
    const u16* Bsl = Bs[s];
    bf16x8 bfr[4], afr[4];
#pragma unroll
    for (int ni = 0; ni < 4; ni++) {
      int row = wc * 64 + ni * 16 + l15;
      bfr[ni] = *(const bf16x8*)(Bsl + row * BK + ((quad ^ (row & 3)) << 3));
    }
#pragma unroll
    for (int mi = 0; mi < 4; mi++) {
      int row = wr * 64 + mi * 16 + l15;
      afr[mi] = *(const bf16x8*)(Asl + row * BK + ((quad ^ (row & 3)) << 3));
    }
    __builtin_amdgcn_s_setprio(1);
#pragma unroll
    for (int mi = 0; mi < 4; mi++)
#pragma unroll
      for (int ni = 0; ni < 4; ni++)
        acc[mi][ni] = MFMA16x16(afr[mi], bfr[ni], acc[mi][ni]);
    __builtin_amdgcn_s_setprio(0);

    if (t + 1 < NT) {
      asm volatile("s_waitcnt vmcnt(0)" ::: "memory");  // t+1 staged
      __builtin_amdgcn_s_barrier();
    }
  }

  const int sel = n0 >> 10;       // 0=Q,1=K,2=V (128-tile never straddles)
  const int nloc = n0 & 1023;
  if (sel < 2) {
    u16* D = (sel == 0) ? qout : kout;
    const float* bias = (sel == 0) ? b0 : b1;
#pragma unroll
    for (int mi = 0; mi < 4; mi++)
#pragma unroll
      for (int ni = 0; ni < 4; ni++) {
        int rb = m0 + wr * 64 + mi * 16 + quad * 4;
        int col = nloc + wc * 64 + ni * 16 + l15;
        float bb = bias[col];
#pragma unroll
        for (int r = 0; r < 4; r++)
          D[(size_t)(rb + r) * 1024 + col] = f2bf(acc[mi][ni][r] + bb);
      }
  } else {
#pragma unroll
    for (int mi = 0; mi < 4; mi++)
#pragma unroll
      for (int ni = 0; ni < 4; ni++) {
        int rb = m0 + wr * 64 + mi * 16 + quad * 4;
        int c = nloc + wc * 64 + ni * 16 + l15;
        float bb = b2[c];
        u16x4 pk;
#pragma unroll
        for (int r = 0; r < 4; r++) pk[r] = f2bf(acc[mi][ni][r] + bb);
        *(u16x4*)(vtout + (size_t)c * 4096 + rb) = pk;
      }
  }
}

// ---------------- out-proj GEMM: 128x128 tile, BK=32, 4-slot ring ----------
// (r14/r16 version — measured best) 4 gloads/wave/stage -> vmcnt(8/4/0)
// counted waits keep 2 K-tiles in flight across barriers. 256 thr =
// 4 waves (2M x 2N), 64 KB LDS.
__global__ __launch_bounds__(256, 2) void gemm_out_kernel(
    const u16* __restrict__ A, const u16* __restrict__ Bt,
    const float* __restrict__ bias, float* __restrict__ fout) {
  constexpr int K = 1024, BK = 32, NT = K / BK;   // NT = 32
  __shared__ __align__(16) u16 ring[4][2][128 * BK];   // 64 KiB

  const int tid = threadIdx.x;
  const int w = tid >> 6, lane = tid & 63;
  const int l15 = lane & 15, quad = lane >> 4;
  const int wr = w >> 1, wc = w & 1;           // 2(M) x 2(N) wave grid
  // XCD-aware swizzle (256 blocks, %8==0 -> simple form bijective)
  const int bid = blockIdx.y * 8 + blockIdx.x;
  const int swz = (bid & 7) * 32 + (bid >> 3);
  const int m0 = (swz >> 3) * 128, n0 = (swz & 7) * 128;
  const int rw = lane >> 2;                    // staging row-in-16
  const int pc = lane & 3;                     // staging phys chunk

  const u16* Ag = A + (size_t)m0 * K;
  const u16* Bg = Bt + (size_t)n0 * K;

  f32x4 acc[4][4] = {};

  auto STAGE = [&](int kt, int s) {
#pragma unroll
    for (int j = 0; j < 2; j++) {
      int row = j * 64 + w * 16 + rw;
      int cl = pc ^ (row & 3);
      gload_lds16(Ag + (size_t)row * K + kt * BK + cl * 8,
                  &ring[s][0][(j * 64 + w * 16) * BK]);
      gload_lds16(Bg + (size_t)row * K + kt * BK + cl * 8,
                  &ring[s][1][(j * 64 + w * 16) * BK]);
    }
  };

  STAGE(0, 0); STAGE(1, 1); STAGE(2, 2);
  asm volatile("s_waitcnt vmcnt(8)" ::: "memory");
  __builtin_amdgcn_s_barrier();

#pragma unroll 1
  for (int t = 0; t < NT; ++t) {
    const int s = t & 3;
    if (t + 3 < NT) STAGE(t + 3, (t + 3) & 3);

    const u16* As = ring[s][0];
    const u16* Bs = ring[s][1];
    bf16x8 bfr[4], afr[4];
#pragma unroll
    for (int ni = 0; ni < 4; ni++) {
      int row = wc * 64 + ni * 16 + l15;
      bfr[ni] = *(const bf16x8*)(Bs + row * BK + ((quad ^ (row & 3)) << 3));
    }
#pragma unroll
    for (int mi = 0; mi < 4; mi++) {
      int row = wr * 64 + mi * 16 + l15;
      afr[mi] = *(const bf16x8*)(As + row * BK + ((quad ^ (row & 3)) << 3));
    }
    __builtin_amdgcn_s_setprio(1);
#pragma unroll
    for (int mi = 0; mi < 4; mi++)
#pragma unroll
      for (int ni = 0; ni < 4; ni++)
        acc[mi][ni] = MFMA16x16(afr[mi], bfr[ni], acc[mi][ni]);
    __builtin_amdgcn_s_setprio(0);

    if (t + 3 < NT)
      asm volatile("s_waitcnt vmcnt(8)" ::: "memory");
    else if (t + 2 < NT)
      asm volatile("s_waitcnt vmcnt(4)" ::: "memory");
    else if (t + 1 < NT)
      asm volatile("s_waitcnt vmcnt(0)" ::: "memory");
    if (t + 1 < NT) __builtin_amdgcn_s_barrier();
  }

#pragma unroll
  for (int mi = 0; mi < 4; mi++)
#pragma unroll
    for (int ni = 0; ni < 4; ni++) {
      int rb = m0 + wr * 64 + mi * 16 + quad * 4;
      int col = n0 + wc * 64 + ni * 16 + l15;
      float bb = bias[col];
#pragma unroll
      for (int r = 0; r < 4; r++)
        fout[(size_t)(rb + r) * 1024 + col] = acc[mi][ni][r] + bb;
    }
}

// ---------------- paired flash attention, j-split wave groups ----------------
// r9 body EXACTLY (~50 us; 64 VGPR, no spill, reg-Q, 48 KB LDS). Flat
// 512-block grid with XCD-locality remap — each XCD (id&7) owns 4 heads;
// K/V+Q working set (~3 MB) fits the 4 MB per-XCD L2 (FETCH 96 -> 14.6 MB).
// __expf kept: native v_exp_f32 path; libm exp2f measured 12% slower (r17).
__global__ __launch_bounds__(512, 4) void attn_kernel(
    const u16* __restrict__ qbuf, const u16* __restrict__ kbuf,
    const u16* __restrict__ vtbuf, u16* __restrict__ ybuf) {
  __shared__ __align__(16) u16 KVs[4][64 * 64];    // 32 KB: K0,K1,V0,V1
  __shared__ __align__(16) u16 Ps[8][16 * 64];     // 16 KB per-wave P

  const int tid = threadIdx.x;
  const int w = tid >> 6, lane = tid & 63;
  const int wq = w & 3, g = w >> 2;
  const int l15 = lane & 15, quad = lane >> 4;
  // XCD-locality remap: id -> (xcd = id&7, x = (id>>3)&15, bhl = id>>7);
  // bh = xcd*4 + bhl. Bijective on [0,512).
  const int id = (int)blockIdx.x;
  const int bh = (id & 7) * 4 + (id >> 7);
  const int qx = (id >> 3) & 15;
  const int b = bh >> 4, h = bh & 15;
  const float slope = exp2f(-0.5f * (float)(h + 1));
  const float slope128 = slope * 128.f;
  const int gsub = (lane & 7) ^ ((lane >> 3) & 7);
  const int rsub = lane >> 3;

  const u16* kbase0 = kbuf + (size_t)b * T * C + h * HD;
  const u16* vtbase0 = vtbuf + (size_t)h * HD * BT + (size_t)b * T;
  u16* Pw = Ps[w];
  // staging role: tile t = w>>1 (0=K of jt0, 1=V of jt0, 2=K of jt1, 3=V of jt1)
  const int st = w >> 1;
  const int skind = st & 1;          // 0=K, 1=V
  const int sjt = st >> 1;           // which j-tile of the pair
  const int srb = (w & 1) * 32;      // 32 rows per wave

#pragma unroll 1
  for (int half = 0; half < 2; half++) {
    const int qt = half == 0 ? (31 - qx) : qx;

    // Q fragments straight from global: lane reads its own output row
    // (qt*64 + wq*16 + l15), 16B at cols [quad*8, quad*8+8) and +32.
    const u16* qb = qbuf + (size_t)(b * T + qt * 64 + wq * 16 + l15) * C + h * HD;
    bf16x8 aq0 = *(const bf16x8*)(qb + quad * 8);
    bf16x8 aq1 = *(const bf16x8*)(qb + 32 + quad * 8);

    f32x4 o[4] = {};
    float lsum[4] = {0.f, 0.f, 0.f, 0.f};
    // br[ni][r] = slope*(j - i) at jt = g (virtual), advances by 2 tiles/iter
    float br[4][4];
    const int ig0 = qt * 64 + wq * 16 + quad * 4;
#pragma unroll
    for (int ni = 0; ni < 4; ni++)
#pragma unroll
      for (int r = 0; r < 4; r++)
        br[ni][r] = slope * (float)(g * 64 + ni * 16 + l15 - ig0 - r);

    const int iters = (qt + 2) >> 1;   // ceil((qt+1)/2)
#pragma unroll 1
    for (int it = 0; it < iters; it++) {
      __syncthreads();  // all waves done with previous K/V frag reads
                        // (and, at it=0, with the prior half's LDS scratch)
      {
        int jtv = 2 * it + sjt;
        int jtr = jtv > qt ? qt : jtv;     // clamp: no OOB, contribution masked
        const u16* base = skind ? (vtbase0 + jtr * 64)
                                : (kbase0 + (size_t)jtr * 64 * C);
        const int stride = skind ? BT : C;
        u16* dst = KVs[skind * 2 + sjt] + srb * 64;
#pragma unroll
        for (int c2 = 0; c2 < 4; c2++)
          gload_lds16(base + (size_t)(srb + c2 * 8 + rsub) * stride + gsub * 8,
                      dst + c2 * 8 * 64);
      }
      __syncthreads();  // staging visible

      const int jtv = 2 * it + g;        // this group's virtual j-tile
      const u16* Kw = KVs[g];
      const u16* Vw = KVs[2 + g];

      // S[16x64] = Q K^T
      f32x4 s[4];
#pragma unroll
      for (int ni = 0; ni < 4; ni++) {
        bf16x8 kf0 = ldsfrag(Kw, ni * 16 + l15, quad);
        bf16x8 kf1 = ldsfrag(Kw, ni * 16 + l15, 4 + quad);
        f32x4 z = {0.f, 0.f, 0.f, 0.f};
        z = MFMA16x16(aq0, kf0, z);
        z = MFMA16x16(aq1, kf1, z);
        s[ni] = z;
      }

      const bool edge = (jtv >= qt);     // diagonal or dead (jtv>qt)
#pragma unroll
      for (int ni = 0; ni < 4; ni++)
#pragma unroll
        for (int r = 0; r < 4; r++) {
          float p = __expf(fmaf(s[ni][r], 0.125f, br[ni][r]));
          // mask by virtual global j vs i (covers diag + dead uniformly)
          if (edge && (jtv * 64 + ni * 16 + l15) > (ig0 + r)) p = 0.f;
          lsum[r] += p;
          int prow = quad * 4 + r, pcol = ni * 16 + l15;
          Pw[prow * 64 + (((pcol >> 3) ^ (prow & 7)) << 3) + (pcol & 7)] = f2bf(p);
          br[ni][r] += slope128;
        }

      bf16x8 pa0 = ldsfrag(Pw, l15, quad);
      bf16x8 pa1 = ldsfrag(Pw, l15, 4 + quad);
#pragma unroll
      for (int ni = 0; ni < 4; ni++) {
        bf16x8 vf0 = ldsfrag(Vw, ni * 16 + l15, quad);
        bf16x8 vf1 = ldsfrag(Vw, ni * 16 + l15, 4 + quad);
        o[ni] = MFMA16x16(pa0, vf0, o[ni]);
        o[ni] = MFMA16x16(pa1, vf1, o[ni]);
      }
    }

    // combine the two groups (pure sums), then normalize + write y
    __syncthreads();  // KVs now reusable as f32 scratch
    float* sc = (float*)KVs;           // 32 KB scratch
    float* Osc = sc + wq * 1024;       // [16 rows][64 d] per wq
    float* Lsc = sc + 4096 + wq * 256; // [16 rows][16 cols] per wq
    if (g == 1) {
#pragma unroll
      for (int ni = 0; ni < 4; ni++)
#pragma unroll
        for (int r = 0; r < 4; r++)
          Osc[(quad * 4 + r) * 64 + ni * 16 + l15] = o[ni][r];
#pragma unroll
      for (int r = 0; r < 4; r++)
        Lsc[(quad * 4 + r) * 16 + l15] = lsum[r];
    }
    __syncthreads();
    if (g == 0) {
#pragma unroll
      for (int ni = 0; ni < 4; ni++)
#pragma unroll
        for (int r = 0; r < 4; r++)
          o[ni][r] += Osc[(quad * 4 + r) * 64 + ni * 16 + l15];
#pragma unroll
      for (int r = 0; r < 4; r++) {
        float l = lsum[r] + Lsc[(quad * 4 + r) * 16 + l15];
        l += __shfl_xor(l, 1);
        l += __shfl_xor(l, 2);
        l += __shfl_xor(l, 4);
        l += __shfl_xor(l, 8);
        float inv = 1.f / l;
        int row_g = b * T + qt * 64 + wq * 16 + quad * 4 + r;
        u16* yrow = ybuf + (size_t)row_g * C + h * HD;
#pragma unroll
        for (int ni = 0; ni < 4; ni++)
          yrow[ni * 16 + l15] = f2bf(o[ni][r] * inv);
      }
    }
  }
}

extern "C" void kernel_launch(void* const* d_in, const int* in_sizes, int n_in,
                              void* d_out, int out_size, void* d_ws, size_t ws_size,
                              hipStream_t stream) {
  (void)in_sizes; (void)n_in; (void)out_size; (void)ws_size;
  const float* x  = (const float*)d_in[0];
  const float* Wq = (const float*)d_in[1];
  const float* bq = (const float*)d_in[2];
  const float* Wk = (const float*)d_in[3];
  const float* bk = (const float*)d_in[4];
  const float* Wv = (const float*)d_in[5];
  const float* bv = (const float*)d_in[6];
  const float* Wo = (const float*)d_in[7];
  const float* bo = (const float*)d_in[8];

  u16* ws = (u16*)d_ws;
  constexpr size_t M1 = 1u << 20;
  u16* wqkvT = ws;               // [3072,1024] = [WqT;WkT;WvT]
  u16* woT   = ws + 3 * M1;      // [1024,1024]
  u16* xc    = ws + 4 * M1;      // [4096,1024] bf16 x
  u16* qbuf  = ws + 8 * M1;      // [4096,1024] bf16 Q (later aliased as y)
  u16* vtbuf = ws + 12 * M1;     // [1024,4096] bf16 V^T
  u16* kbuf  = (u16*)d_out;      // bf16 K staged in d_out (16 MB fp32 buffer)
  u16* ybuf  = qbuf;             // safe alias: block overwrites only its own Q tiles

  prep_kernel<<<6144, 256, 0, stream>>>(x, xc, Wq, Wk, Wv, Wo, wqkvT, woT);
  gemm_qkv_kernel<<<dim3(24, 16), 512, 0, stream>>>(
      xc, wqkvT, bq, bk, bv, qbuf, kbuf, vtbuf);
  attn_kernel<<<dim3(512), 512, 0, stream>>>(qbuf, kbuf, vtbuf, ybuf);
  gemm_out_kernel<<<dim3(8, 32), 256, 0, stream>>>(ybuf, woT, bo, (float*)d_out);
}